// Round 5
// baseline (3502.201 us; speedup 1.0000x reference)
//
#include <hip/hip_runtime.h>
#include <hip/hip_bf16.h>

// Problem constants: B=32, T=512, D=768, H=256, K=32
// Outputs: d_out[0] = loss (f32), d_out[1 + b*512 + t] = preds as float.

#define NB 32
#define NT 512
#define ND 768
#define NH 256
#define NK 32

// ---------------------------------------------------------------------------
// K1.5: transpose W_hh into Wt4[(dir*256 + k)*256 + j] =
//   {W[0*256+j][k], W[1*256+j][k], W[2*256+j][k], W[3*256+j][k]}
// ---------------------------------------------------------------------------
__global__ __launch_bounds__(256) void k_wt4(const float* __restrict__ Whf,
                                             const float* __restrict__ Whb,
                                             float4* __restrict__ Wt4) {
    int gid = blockIdx.x * 256 + threadIdx.x;
    if (gid >= 131072) return;
    int dir = gid >> 16;
    int k   = (gid >> 8) & 255;
    int j   = gid & 255;
    const float* W = dir ? Whb : Whf;
    Wt4[gid] = make_float4(W[(size_t)(0 * 256 + j) * 256 + k],
                           W[(size_t)(1 * 256 + j) * 256 + k],
                           W[(size_t)(2 * 256 + j) * 256 + k],
                           W[(size_t)(3 * 256 + j) * 256 + k]);
}

__device__ __forceinline__ float sigm(float x) { return 1.f / (1.f + expf(-x)); }

// ---------------------------------------------------------------------------
// K2-FUSED v3: SGEMM + LSTM in ONE kernel, pipelined via data-is-the-flag.
//
// MINIMAL DELTA from the PASSING R3 fusion (absmax 0.0): the ONLY structural
// change is dispatch order — LSTM blocks are bid < 256 (first), SGEMM blocks
// bid >= 256 — plus __launch_bounds__(256, 2) which caps VGPR at 256 and
// guarantees >=2 blocks/CU capacity. Consequence: even with worst-case
// depth-first packing (2 LSTM blocks/CU on 128 CUs), the other half of the
// machine runs SGEMM; the SGEMM queue always drains (SGEMM blocks never
// wait), so C is always produced. Deadlock-impossible by construction.
//
// R4's failed extras (s_setprio, plain-load C fast path) are REVERTED:
// the C consume path below is R3's verified code verbatim — agent-scope
// atomic prefetch at loop top (latency hides under the h-poll), sentinel
// re-check + slept atomic re-poll after SYNC_B.
//
//  LSTM block (bid<256): EXACT R2 recurrence structure (verified at 1055us).
//  SGEMM worker (bid>=256): m-tiles priority-scheduled on device from
//    `lengths` (rows needed at small LSTM steps first: fwd needs row r at
//    step r; bwd at step len-1-r). Publishes C with packed 8B agent-scope
//    relaxed atomic stores (C pre-poisoned with 0xFFFFFFFF NaN sentinel;
//    finite dot products never equal it).
// ---------------------------------------------------------------------------
__global__ __launch_bounds__(256, 2) void k_fused(const float* __restrict__ A,
                                                  const float* __restrict__ Wf,
                                                  const float* __restrict__ Wb,
                                                  float* __restrict__ C,
                                                  const float4* __restrict__ Wt4,
                                                  const float* __restrict__ b_f,
                                                  const float* __restrict__ b_b,
                                                  const int* __restrict__ lengths,
                                                  float* __restrict__ h_f,
                                                  float* __restrict__ h_b) {
    __shared__ float As[16][132];
    __shared__ float Bs[16][132];
    __shared__ int keys[128];
    __shared__ int sched[128];
    __shared__ float4 hsh4[64];        // h(t-1): 256 floats, one batch
    __shared__ float4 part[4][64];     // [k-quad][jj] partial gate sums
    __shared__ float4 bias4[64];

    const int tid = threadIdx.x;
    const int bid = blockIdx.x;

    if (bid >= 256) {
        // =================== SGEMM worker ===================
        const int sgid = bid - 256;
        // --- on-device priority schedule of the 128 m-tiles ---
        if (tid < 128) {
            int b = tid >> 2, q = tid & 3;
            int len = lengths[b];
            int lo = q * 128, hi = lo + 127;
            int fwd = lo;                       // fwd consumes row r at step r
            int bwd;
            if (len - 1 > hi)       bwd = len - 1 - hi;   // tile below last valid row
            else if (len - 1 >= lo) bwd = 0;              // len-1 inside tile
            else                    bwd = lo;             // rows >= len: step r
            int need = fwd < bwd ? fwd : bwd;
            keys[tid] = need * 128 + tid;       // unique, deterministic
        }
        __syncthreads();
        if (tid < 128) {
            int my = keys[tid];
            int rank = 0;
#pragma unroll 4
            for (int y = 0; y < 128; ++y) rank += (keys[y] < my);
            sched[rank] = tid;
        }
        __syncthreads();

        const int by = sched[sgid >> 4];   // priority-ranked m tile
        const int bx = sgid & 15;          // n tile 0..15
        const int tx = tid & 15, ty = tid >> 4;
        const int sm = tid >> 2;           // 0..63
        const int sk = (tid & 3) * 4;      // 0,4,8,12
        float acc[8][8];
#pragma unroll
        for (int i = 0; i < 8; ++i)
#pragma unroll
            for (int j = 0; j < 8; ++j) acc[i][j] = 0.f;

        for (int k0 = 0; k0 < ND; k0 += 16) {
#pragma unroll
            for (int h = 0; h < 2; ++h) {
                int m = sm + h * 64;
                float4 v = *(const float4*)(A + (size_t)(by * 128 + m) * ND + k0 + sk);
                As[sk + 0][m] = v.x; As[sk + 1][m] = v.y; As[sk + 2][m] = v.z; As[sk + 3][m] = v.w;
                int n = sm + h * 64;
                int gn = bx * 128 + n;
                const float* Wrow = (gn < 1024) ? (Wf + (size_t)gn * ND) : (Wb + (size_t)(gn - 1024) * ND);
                float4 w = *(const float4*)(Wrow + k0 + sk);
                Bs[sk + 0][n] = w.x; Bs[sk + 1][n] = w.y; Bs[sk + 2][n] = w.z; Bs[sk + 3][n] = w.w;
            }
            __syncthreads();
#pragma unroll
            for (int kk = 0; kk < 16; ++kk) {
                float a[8], b[8];
                *(float4*)&a[0] = *(const float4*)&As[kk][ty * 4];
                *(float4*)&a[4] = *(const float4*)&As[kk][64 + ty * 4];
                *(float4*)&b[0] = *(const float4*)&Bs[kk][tx * 4];
                *(float4*)&b[4] = *(const float4*)&Bs[kk][64 + tx * 4];
#pragma unroll
                for (int i = 0; i < 8; ++i)
#pragma unroll
                    for (int j = 0; j < 8; ++j)
                        acc[i][j] = fmaf(a[i], b[j], acc[i][j]);
            }
            __syncthreads();
        }
        // --- publish: packed 8B agent-scope relaxed atomic stores ---
#pragma unroll
        for (int i = 0; i < 8; ++i) {
            int m = by * 128 + ((i < 4) ? (ty * 4 + i) : (64 + ty * 4 + (i - 4)));
            float* Crow = C + (size_t)m * 2048 + bx * 128;
#pragma unroll
            for (int hh = 0; hh < 2; ++hh) {
                float* p = Crow + hh * 64 + tx * 4;
#pragma unroll
                for (int w = 0; w < 2; ++w) {
                    float2 v = make_float2(acc[i][hh * 4 + 2 * w], acc[i][hh * 4 + 2 * w + 1]);
                    __hip_atomic_store((unsigned long long*)(p + 2 * w),
                                       *(unsigned long long*)&v,
                                       __ATOMIC_RELAXED, __HIP_MEMORY_SCOPE_AGENT);
                }
            }
        }
        return;
    }

    // =================== LSTM block (R2 structure, verified) ===================
    const int lid = bid;                  // 0..255
    const int g = lid & 63, s = lid >> 6;
    const int b = g & 31, dir = g >> 5;
    const int j0 = s * 64;
    const float* bias = dir ? b_b : b_f;
    float* hdir = dir ? h_b : h_f;

    if (tid < 64)
        bias4[tid] = make_float4(bias[j0 + tid], bias[256 + j0 + tid],
                                 bias[512 + j0 + tid], bias[768 + j0 + tid]);

    const int jj = tid & 63, kq = tid >> 6;   // j-column, k-quad (64 k each)
    float4 wreg[64];
    {
        const float4* wb = Wt4 + ((size_t)dir * 256 + kq * 64) * 256 + j0 + jj;
#pragma unroll
        for (int i = 0; i < 64; ++i) wreg[i] = wb[(size_t)i * 256];
    }
    const int mylen = lengths[b];
    float creg = 0.f;
    float* hshf = (float*)hsh4;
    __syncthreads();

    for (int t = 0; t < NT; ++t) {
        // issue this step's C-row loads (agent atomics, R3-verified path);
        // validated after SYNC_B. Issued before the h-poll so latency hides.
        float4 pre = make_float4(0.f, 0.f, 0.f, 0.f);
        const float* Crow = nullptr;
        if (tid < 64) {
            int src_t = t;
            if (dir) src_t = (t < mylen) ? (mylen - 1 - t) : t;
            Crow = C + (size_t)(b * 512 + src_t) * 2048 + dir * 1024 + j0 + tid;
            pre.x = __hip_atomic_load(Crow + 0,   __ATOMIC_RELAXED, __HIP_MEMORY_SCOPE_AGENT);
            pre.y = __hip_atomic_load(Crow + 256, __ATOMIC_RELAXED, __HIP_MEMORY_SCOPE_AGENT);
            pre.z = __hip_atomic_load(Crow + 512, __ATOMIC_RELAXED, __HIP_MEMORY_SCOPE_AGENT);
            pre.w = __hip_atomic_load(Crow + 768, __ATOMIC_RELAXED, __HIP_MEMORY_SCOPE_AGENT);
        }
        if (t > 0) {
            // poll h(t-1): one value per thread; data is the flag
            const float* hp = hdir + ((size_t)b * 512 + (t - 1)) * 256 + tid;
            float v;
            int guard = 0;
            for (;;) {
                v = __hip_atomic_load(hp, __ATOMIC_RELAXED, __HIP_MEMORY_SCOPE_AGENT);
                if (__float_as_uint(v) != 0xFFFFFFFFu) break;
                if (++guard > (1 << 24)) break;   // liveness valve (~>1s)
            }
            hshf[tid] = v;
            __syncthreads();      // SYNC_A: hsh ready for all readers
        }
        float4 acc = make_float4(0.f, 0.f, 0.f, 0.f);
        if (t > 0) {
#pragma unroll
            for (int c = 0; c < 16; ++c) {
                float ha[4];
                *(float4*)ha = hsh4[kq * 16 + c];   // wave-broadcast read
#pragma unroll
                for (int i = 0; i < 4; ++i) {
                    float4 wv = wreg[c * 4 + i];
                    acc.x = fmaf(wv.x, ha[i], acc.x);
                    acc.y = fmaf(wv.y, ha[i], acc.y);
                    acc.z = fmaf(wv.z, ha[i], acc.z);
                    acc.w = fmaf(wv.w, ha[i], acc.w);
                }
            }
        }
        part[kq][jj] = acc;
        __syncthreads();          // SYNC_B: part ready for reducers
        if (tid < 64) {
            // validate C row (sentinel => SGEMM not there yet; slept re-poll)
            if (__float_as_uint(pre.x) == 0xFFFFFFFFu ||
                __float_as_uint(pre.y) == 0xFFFFFFFFu ||
                __float_as_uint(pre.z) == 0xFFFFFFFFu ||
                __float_as_uint(pre.w) == 0xFFFFFFFFu) {
                int guard = 0;
                do {
                    __builtin_amdgcn_s_sleep(2);
                    pre.x = __hip_atomic_load(Crow + 0,   __ATOMIC_RELAXED, __HIP_MEMORY_SCOPE_AGENT);
                    pre.y = __hip_atomic_load(Crow + 256, __ATOMIC_RELAXED, __HIP_MEMORY_SCOPE_AGENT);
                    pre.z = __hip_atomic_load(Crow + 512, __ATOMIC_RELAXED, __HIP_MEMORY_SCOPE_AGENT);
                    pre.w = __hip_atomic_load(Crow + 768, __ATOMIC_RELAXED, __HIP_MEMORY_SCOPE_AGENT);
                    if (++guard > (1 << 22)) break;   // liveness valve
                } while (__float_as_uint(pre.x) == 0xFFFFFFFFu ||
                         __float_as_uint(pre.y) == 0xFFFFFFFFu ||
                         __float_as_uint(pre.z) == 0xFFFFFFFFu ||
                         __float_as_uint(pre.w) == 0xFFFFFFFFu);
            }
            float4 b4 = bias4[tid];
            float sx = pre.x + b4.x, sy = pre.y + b4.y, sz = pre.z + b4.z, sw = pre.w + b4.w;
#pragma unroll
            for (int q = 0; q < 4; ++q) {
                float4 p = part[q][tid];
                sx += p.x; sy += p.y; sz += p.z; sw += p.w;
            }
            float ig = sigm(sx), fg = sigm(sy), gt = tanhf(sz), og = sigm(sw);
            creg = fg * creg + ig * gt;
            float hn = og * tanhf(creg);
            __hip_atomic_store(hdir + ((size_t)b * 512 + t) * 256 + j0 + tid,
                               hn, __ATOMIC_RELAXED, __HIP_MEMORY_SCOPE_AGENT);
        }
        // no trailing barrier: the store IS the publication (write-once slots)
    }
}

// ---------------------------------------------------------------------------
// K3: emissions  em[b][t][k] = hcat . W_clf[k] + b_clf[k]
// ---------------------------------------------------------------------------
__global__ __launch_bounds__(256) void k_em(const float* __restrict__ hf,
                                            const float* __restrict__ hb,
                                            const float* __restrict__ Wclf,
                                            const float* __restrict__ bclf,
                                            const int* __restrict__ lengths,
                                            float* __restrict__ em) {
    extern __shared__ float4 wc4[];   // [128][32]: wc4[jq*32+ko] = Wclf[ko][4jq..+3]
    const int tid = threadIdx.x;
    for (int idx = tid; idx < 4096; idx += 256) {
        int jq = idx >> 5, ko = idx & 31;
        wc4[idx] = *(const float4*)(Wclf + (size_t)ko * 512 + jq * 4);
    }
    __syncthreads();
    const int r = tid >> 5, ko = tid & 31;
    const int m = blockIdx.x * 8 + r;
    const int b = m >> 9, t = m & 511;
    const int len = lengths[b];
    const int rev = (t < len) ? (len - 1 - t) : t;
    const float* hfr = hf + (size_t)m * 256;
    const float* hbr = hb + (size_t)(b * 512 + rev) * 256;
    float acc = bclf[ko];
#pragma unroll 4
    for (int jq = 0; jq < 64; ++jq) {
        float4 h4 = *(const float4*)(hfr + jq * 4);
        float4 ww = wc4[jq * 32 + ko];
        acc += h4.x * ww.x + h4.y * ww.y + h4.z * ww.z + h4.w * ww.w;
    }
#pragma unroll 4
    for (int jq = 0; jq < 64; ++jq) {
        float4 h4 = *(const float4*)(hbr + jq * 4);
        float4 ww = wc4[(64 + jq) * 32 + ko];
        acc += h4.x * ww.x + h4.y * ww.y + h4.z * ww.z + h4.w * ww.w;
    }
    em[(size_t)m * 32 + ko] = acc;
}

// ---------------------------------------------------------------------------
// K4: CRF forward (logZ, num) and Viterbi (+backtrace).
// ---------------------------------------------------------------------------
__global__ __launch_bounds__(64) void k_crfvit(const float* __restrict__ em,
                                               const int* __restrict__ targets,
                                               const int* __restrict__ lengths,
                                               const float* __restrict__ start_t,
                                               const float* __restrict__ end_t,
                                               const float* __restrict__ trans,
                                               float* __restrict__ numv,
                                               float* __restrict__ logZv,
                                               float* __restrict__ out) {
    __shared__ float trans_s[32][33];
    __shared__ float vec[32];
    __shared__ unsigned char hist[511 * 32];
    const int tid = threadIdx.x;
    const int b = blockIdx.x & 31;
    const int mode = blockIdx.x >> 5;
    for (int idx = tid; idx < 1024; idx += 64) trans_s[idx >> 5][idx & 31] = trans[idx];
    const int len = lengths[b];
    const float* emb = em + (size_t)b * 512 * 32;
    const int k = tid & 31, half = tid >> 5;
    if (tid < 32) vec[tid] = start_t[tid] + emb[tid];
    __syncthreads();

    if (mode == 0) {
        for (int t = 1; t < NT; ++t) {
            bool mv = t < len;
            int kp0 = half * 16;
            float m = -1e30f;
#pragma unroll 4
            for (int i = 0; i < 16; ++i)
                m = fmaxf(m, vec[kp0 + i] + trans_s[kp0 + i][k]);
            float m2 = fmaxf(m, __shfl_xor(m, 32));
            float ssum = 0.f;
#pragma unroll 4
            for (int i = 0; i < 16; ++i)
                ssum += __expf(vec[kp0 + i] + trans_s[kp0 + i][k] - m2);
            ssum += __shfl_xor(ssum, 32);
            float anew = m2 + __logf(ssum) + emb[t * 32 + k];
            __syncthreads();
            if (half == 0 && mv) vec[k] = anew;
            __syncthreads();
        }
        float val = (tid < 32) ? vec[tid] + end_t[tid] : -1e30f;
        float m = val;
#pragma unroll
        for (int off = 32; off >= 1; off >>= 1) m = fmaxf(m, __shfl_xor(m, off));
        float e = (tid < 32) ? __expf(val - m) : 0.f;
#pragma unroll
        for (int off = 32; off >= 1; off >>= 1) e += __shfl_xor(e, off);
        if (tid == 0) logZv[b] = m + __logf(e);
        // numerator
        const int* tg = targets + b * 512;
        float partial = 0.f;
        for (int t = 1 + tid; t < NT; t += 64) {
            if (t < len) {
                int y0 = tg[t - 1], y1 = tg[t];
                partial += trans_s[y0][y1] + emb[t * 32 + y1];
            }
        }
#pragma unroll
        for (int off = 32; off >= 1; off >>= 1) partial += __shfl_xor(partial, off);
        if (tid == 0) {
            int y00 = tg[0];
            int yl = tg[len - 1];
            numv[b] = partial + start_t[y00] + emb[y00] + end_t[yl];
        }
    } else {
        for (int t = 1; t < NT; ++t) {
            bool mv = t < len;
            int kp0 = half * 16;
            float e = emb[t * 32 + k];
            float m = -1e30f; int mi = kp0;
#pragma unroll 4
            for (int i = 0; i < 16; ++i) {
                float v = (vec[kp0 + i] + trans_s[kp0 + i][k]) + e;
                if (v > m) { m = v; mi = kp0 + i; }
            }
            float mo = __shfl_xor(m, 32);
            int io = __shfl_xor(mi, 32);
            float mlow = half ? mo : m;   int ilow = half ? io : mi;
            float mhigh = half ? m : mo;  int ihigh = half ? mi : io;
            float bm; int bi;
            if (mhigh > mlow) { bm = mhigh; bi = ihigh; } else { bm = mlow; bi = ilow; }
            __syncthreads();
            if (half == 0) {
                hist[(t - 1) * 32 + k] = (unsigned char)(mv ? bi : k);
                if (mv) vec[k] = bm;
            }
            __syncthreads();
        }
        float val = (tid < 32) ? vec[tid] + end_t[tid] : -1e30f;
        int idx = (tid < 32) ? tid : 63;
#pragma unroll
        for (int off = 32; off >= 1; off >>= 1) {
            float vo = __shfl_xor(val, off);
            int io = __shfl_xor(idx, off);
            if (vo > val || (vo == val && io < idx)) { val = vo; idx = io; }
        }
        int cur = idx;
        float* ob = out + 1 + (size_t)b * 512;
        if (tid == 0) ob[511] = (511 < len) ? (float)cur : 0.f;
        for (int t2 = 510; t2 >= 0; --t2) {
            cur = hist[t2 * 32 + cur];
            if (tid == 0) ob[t2] = (t2 < len) ? (float)cur : 0.f;
        }
    }
}

// ---------------------------------------------------------------------------
// K5: loss = -mean(num - logZ)
// ---------------------------------------------------------------------------
__global__ __launch_bounds__(64) void k_loss(const float* __restrict__ numv,
                                             const float* __restrict__ logZv,
                                             float* __restrict__ out) {
    int tid = threadIdx.x;
    float v = (tid < 32) ? (logZv[tid] - numv[tid]) : 0.f;
#pragma unroll
    for (int off = 32; off >= 1; off >>= 1) v += __shfl_xor(v, off);
    if (tid == 0) out[0] = v / 32.f;
}

// ---------------------------------------------------------------------------
extern "C" void kernel_launch(void* const* d_in, const int* in_sizes, int n_in,
                              void* d_out, int out_size, void* d_ws, size_t ws_size,
                              hipStream_t stream) {
    const float* x       = (const float*)d_in[0];
    const int*   lengths = (const int*)d_in[1];
    // d_in[2] = mask (recomputed from lengths)
    const int*   targets = (const int*)d_in[3];
    const float* W_ih_f  = (const float*)d_in[4];
    const float* W_hh_f  = (const float*)d_in[5];
    const float* b_f     = (const float*)d_in[6];
    const float* W_ih_b  = (const float*)d_in[7];
    const float* W_hh_b  = (const float*)d_in[8];
    const float* b_b     = (const float*)d_in[9];
    const float* W_clf   = (const float*)d_in[10];
    const float* b_clf   = (const float*)d_in[11];
    const float* start_t = (const float*)d_in[12];
    const float* end_t   = (const float*)d_in[13];
    const float* trans   = (const float*)d_in[14];
    float* out = (float*)d_out;
    float* ws = (float*)d_ws;

    float* C     = ws;                                   // 16384*2048
    float* h_f   = C + (size_t)16384 * 2048;             // 32*512*256
    float* h_b   = h_f + (size_t)32 * 512 * 256;         // 32*512*256
    float* em    = h_b + (size_t)32 * 512 * 256;         // 32*512*32
    float4* Wt4  = (float4*)(em + (size_t)32 * 512 * 32);// 131072 float4
    float* numv  = (float*)(Wt4 + 131072);               // 32
    float* logZv = numv + 32;                            // 32

    // Poison C and h with the sentinel bit pattern every launch
    // (graph-replay safe: this is the per-iteration reset of the data-flags).
    hipMemsetAsync(C,   0xFF, (size_t)16384 * 2048 * sizeof(float), stream);
    hipMemsetAsync(h_f, 0xFF, (size_t)2 * 32 * 512 * 256 * sizeof(float), stream);
    k_wt4<<<512, 256, 0, stream>>>(W_hh_f, W_hh_b, Wt4);
    k_fused<<<2304, 256, 0, stream>>>(x, W_ih_f, W_ih_b, C, Wt4, b_f, b_b,
                                      lengths, h_f, h_b);
    k_em<<<2048, 256, 65536, stream>>>(h_f, h_b, W_clf, b_clf, lengths, em);
    k_crfvit<<<64, 64, 0, stream>>>(em, targets, lengths, start_t, end_t, trans, numv, logZv, out);
    k_loss<<<1, 64, 0, stream>>>(numv, logZv, out);
}

// Round 6
// 2562.807 us; speedup vs baseline: 1.3665x; 1.3665x over previous
//
#include <hip/hip_runtime.h>
#include <hip/hip_bf16.h>

// Problem constants: B=32, T=512, D=768, H=256, K=32
// Outputs: d_out[0] = loss (f32), d_out[1 + b*512 + t] = preds as float.

#define NB 32
#define NT 512
#define ND 768
#define NH 256
#define NK 32

// ---------------------------------------------------------------------------
// K1: SGEMM  C[16384][2048] = x[16384][768] @ [W_ih_f | W_ih_b]^T
// 128x128 tile, 8x8 per thread, BK=16, fp32 — now DOUBLE-BUFFERED:
// one barrier per K-iter, next tile's global loads issued before compute.
// Same per-output summation order as the verified R2 kernel.
// ---------------------------------------------------------------------------
__global__ __launch_bounds__(256) void k_sgemm(const float* __restrict__ A,
                                               const float* __restrict__ Wf,
                                               const float* __restrict__ Wb,
                                               float* __restrict__ C) {
    __shared__ float As[2][16][132];
    __shared__ float Bs[2][16][132];
    const int tid = threadIdx.x;
    const int bx = blockIdx.x;   // n tile: 0..15
    const int by = blockIdx.y;   // m tile: 0..127
    const int tx = tid & 15, ty = tid >> 4;
    const int sm = tid >> 2;           // 0..63
    const int sk = (tid & 3) * 4;      // 0,4,8,12
    float acc[8][8];
#pragma unroll
    for (int i = 0; i < 8; ++i)
#pragma unroll
        for (int j = 0; j < 8; ++j) acc[i][j] = 0.f;

    const float* Arow0 = A + (size_t)(by * 128 + sm) * ND + sk;
    const float* Arow1 = A + (size_t)(by * 128 + 64 + sm) * ND + sk;
    const int gn0 = bx * 128 + sm, gn1 = gn0 + 64;
    const float* W0 = (gn0 < 1024) ? (Wf + (size_t)gn0 * ND + sk) : (Wb + (size_t)(gn0 - 1024) * ND + sk);
    const float* W1 = (gn1 < 1024) ? (Wf + (size_t)gn1 * ND + sk) : (Wb + (size_t)(gn1 - 1024) * ND + sk);

    // prologue: stage k0=0 into buffer 0
    {
        float4 a0 = *(const float4*)(Arow0);
        float4 a1 = *(const float4*)(Arow1);
        float4 w0 = *(const float4*)(W0);
        float4 w1 = *(const float4*)(W1);
        As[0][sk + 0][sm] = a0.x; As[0][sk + 1][sm] = a0.y; As[0][sk + 2][sm] = a0.z; As[0][sk + 3][sm] = a0.w;
        As[0][sk + 0][64 + sm] = a1.x; As[0][sk + 1][64 + sm] = a1.y; As[0][sk + 2][64 + sm] = a1.z; As[0][sk + 3][64 + sm] = a1.w;
        Bs[0][sk + 0][sm] = w0.x; Bs[0][sk + 1][sm] = w0.y; Bs[0][sk + 2][sm] = w0.z; Bs[0][sk + 3][sm] = w0.w;
        Bs[0][sk + 0][64 + sm] = w1.x; Bs[0][sk + 1][64 + sm] = w1.y; Bs[0][sk + 2][64 + sm] = w1.z; Bs[0][sk + 3][64 + sm] = w1.w;
    }
    __syncthreads();

    int cur = 0;
    for (int k0 = 0; k0 < ND; k0 += 16) {
        const bool more = (k0 + 16) < ND;
        float4 na0, na1, nw0, nw1;
        if (more) {   // issue next tile's loads; latency hides under compute
            na0 = *(const float4*)(Arow0 + k0 + 16);
            na1 = *(const float4*)(Arow1 + k0 + 16);
            nw0 = *(const float4*)(W0 + k0 + 16);
            nw1 = *(const float4*)(W1 + k0 + 16);
        }
#pragma unroll
        for (int kk = 0; kk < 16; ++kk) {
            float a[8], b[8];
            *(float4*)&a[0] = *(const float4*)&As[cur][kk][ty * 4];
            *(float4*)&a[4] = *(const float4*)&As[cur][kk][64 + ty * 4];
            *(float4*)&b[0] = *(const float4*)&Bs[cur][kk][tx * 4];
            *(float4*)&b[4] = *(const float4*)&Bs[cur][kk][64 + tx * 4];
#pragma unroll
            for (int i = 0; i < 8; ++i)
#pragma unroll
                for (int j = 0; j < 8; ++j)
                    acc[i][j] = fmaf(a[i], b[j], acc[i][j]);
        }
        if (more) {
            const int nxt = cur ^ 1;   // safe: last read of nxt was before prev barrier
            As[nxt][sk + 0][sm] = na0.x; As[nxt][sk + 1][sm] = na0.y; As[nxt][sk + 2][sm] = na0.z; As[nxt][sk + 3][sm] = na0.w;
            As[nxt][sk + 0][64 + sm] = na1.x; As[nxt][sk + 1][64 + sm] = na1.y; As[nxt][sk + 2][64 + sm] = na1.z; As[nxt][sk + 3][64 + sm] = na1.w;
            Bs[nxt][sk + 0][sm] = nw0.x; Bs[nxt][sk + 1][sm] = nw0.y; Bs[nxt][sk + 2][sm] = nw0.z; Bs[nxt][sk + 3][sm] = nw0.w;
            Bs[nxt][sk + 0][64 + sm] = nw1.x; Bs[nxt][sk + 1][64 + sm] = nw1.y; Bs[nxt][sk + 2][64 + sm] = nw1.z; Bs[nxt][sk + 3][64 + sm] = nw1.w;
            __syncthreads();
            cur = nxt;
        }
    }
#pragma unroll
    for (int i = 0; i < 8; ++i) {
        int m = by * 128 + ((i < 4) ? (ty * 4 + i) : (64 + ty * 4 + (i - 4)));
        float* Crow = C + (size_t)m * 2048 + bx * 128;
        *(float4*)(Crow + tx * 4)      = make_float4(acc[i][0], acc[i][1], acc[i][2], acc[i][3]);
        *(float4*)(Crow + 64 + tx * 4) = make_float4(acc[i][4], acc[i][5], acc[i][6], acc[i][7]);
    }
}

// ---------------------------------------------------------------------------
// K1.5: transpose W_hh into Wt4[(dir*256 + k)*256 + j] =
//   {W[0*256+j][k], W[1*256+j][k], W[2*256+j][k], W[3*256+j][k]}
// ---------------------------------------------------------------------------
__global__ __launch_bounds__(256) void k_wt4(const float* __restrict__ Whf,
                                             const float* __restrict__ Whb,
                                             float4* __restrict__ Wt4) {
    int gid = blockIdx.x * 256 + threadIdx.x;
    if (gid >= 131072) return;
    int dir = gid >> 16;
    int k   = (gid >> 8) & 255;
    int j   = gid & 255;
    const float* W = dir ? Whb : Whf;
    Wt4[gid] = make_float4(W[(size_t)(0 * 256 + j) * 256 + k],
                           W[(size_t)(1 * 256 + j) * 256 + k],
                           W[(size_t)(2 * 256 + j) * 256 + k],
                           W[(size_t)(3 * 256 + j) * 256 + k]);
}

// ---------------------------------------------------------------------------
// K2: LSTM recurrence v3 — WAVE-AUTONOMOUS, BARRIER-FREE.
// Split topology (R2, verified): 64 groups = (dir,batch) x 4 j-slice blocks,
// grid 256 x 256, C fully materialized before launch (plain C loads).
//
// New thread mapping: tid -> (j = tid>>2 in [0,64), kq = tid&3). Lane holds
// W[all 4 gates][j0+j][k], k in [64kq, 64kq+64) (same 256 floats as R2).
// Per step, each WAVE (16 j x 4 kq) is self-contained:
//   - every lane polls 4 h-dims (two packed 8B agent atomic loads,
//     sentinel 0xFFFFFFFF = NaN; h in (-1,1) can never equal it)
//   - distributes via the wave's private LDS row (wave lockstep =>
//     no __syncthreads, just lgkmcnt(0))
//   - FMAs its own kq k-slice
//   - 2-round shfl_xor butterfly over kq completes gate sums IN-REGISTER
//   - all 4 kq lanes redundantly compute gates/c/h (bitwise-identical IEEE
//     ops => replicated c state is exact); kq==0 lane stores h.
// Removed vs R2: SYNC_A, SYNC_B, part[] LDS round-trip, wave0-only serial
// reduce. Cross-block protocol (write-once h slots, sentinel poll) unchanged.
// Precise expf/tanhf (Viterbi preds are sensitive to h error).
// ---------------------------------------------------------------------------
__device__ __forceinline__ float sigm(float x) { return 1.f / (1.f + expf(-x)); }

__global__ __launch_bounds__(256, 1) void k_lstm4(const float* __restrict__ C,
                                                  const float4* __restrict__ Wt4,
                                                  const float* __restrict__ b_f,
                                                  const float* __restrict__ b_b,
                                                  const int* __restrict__ lengths,
                                                  float* __restrict__ h_f,
                                                  float* __restrict__ h_b) {
    __shared__ float hsh[4][272];   // per-wave h(t-1); 64-f slices padded to 68 (bank-spread, 16B-aligned)
    const int tid = threadIdx.x;
    const int g = blockIdx.x & 63, s = blockIdx.x >> 6;
    const int b = g & 31, dir = g >> 5;
    const int j0 = s * 64;
    const float* bias = dir ? b_b : b_f;
    float* hdir = dir ? h_b : h_f;

    const int j = tid >> 2;        // 0..63
    const int kq = tid & 3;        // k-quad
    const int w = tid >> 6;        // wave id
    const int lane = tid & 63;

    float4 wreg[64];
    {
        const float4* wb = Wt4 + ((size_t)dir * 256 + kq * 64) * 256 + j0 + j;
#pragma unroll
        for (int i = 0; i < 64; ++i) wreg[i] = wb[(size_t)i * 256];
    }
    float4 breg = make_float4(0.f, 0.f, 0.f, 0.f);
    if (kq == 0)
        breg = make_float4(bias[j0 + j], bias[256 + j0 + j],
                           bias[512 + j0 + j], bias[768 + j0 + j]);
    const int mylen = lengths[b];
    float creg = 0.f;

    for (int t = 0; t < NT; ++t) {
        // C-row gate biases for this step (plain loads; C is complete).
        // Issued before the poll so latency hides under it.
        float4 pre = make_float4(0.f, 0.f, 0.f, 0.f);
        if (kq == 0) {
            int src_t = t;
            if (dir) src_t = (t < mylen) ? (mylen - 1 - t) : t;
            const float* Crow = C + (size_t)(b * 512 + src_t) * 2048 + dir * 1024 + j0 + j;
            pre.x = Crow[0]; pre.y = Crow[256]; pre.z = Crow[512]; pre.w = Crow[768];
        }
        float4 acc = make_float4(0.f, 0.f, 0.f, 0.f);
        if (t > 0) {
            // wave-autonomous poll: lane owns dims [4*lane, 4*lane+4)
            const float* hp = hdir + ((size_t)b * 512 + (t - 1)) * 256 + 4 * lane;
            unsigned long long u0, u1;
            int guard = 0;
            for (;;) {
                u0 = __hip_atomic_load((const unsigned long long*)hp,
                                       __ATOMIC_RELAXED, __HIP_MEMORY_SCOPE_AGENT);
                u1 = __hip_atomic_load((const unsigned long long*)(hp + 2),
                                       __ATOMIC_RELAXED, __HIP_MEMORY_SCOPE_AGENT);
                if ((unsigned)(u0 & 0xFFFFFFFFu) != 0xFFFFFFFFu &&
                    (unsigned)(u0 >> 32)        != 0xFFFFFFFFu &&
                    (unsigned)(u1 & 0xFFFFFFFFu) != 0xFFFFFFFFu &&
                    (unsigned)(u1 >> 32)        != 0xFFFFFFFFu) break;
                if (++guard > (1 << 24)) break;   // liveness valve
            }
            // distribute within the wave via its private LDS row
            const int d0 = 4 * lane;
            float* dst = &hsh[w][(d0 >> 6) * 68 + (d0 & 63)];
            float lo0 = __uint_as_float((unsigned)(u0 & 0xFFFFFFFFu));
            float hi0 = __uint_as_float((unsigned)(u0 >> 32));
            float lo1 = __uint_as_float((unsigned)(u1 & 0xFFFFFFFFu));
            float hi1 = __uint_as_float((unsigned)(u1 >> 32));
            *(float4*)dst = make_float4(lo0, hi0, lo1, hi1);
            asm volatile("s_waitcnt lgkmcnt(0)" ::: "memory");
            __builtin_amdgcn_sched_barrier(0);
            // FMA over own kq slice (16-lane broadcast reads, conflict-free)
            const float* src = &hsh[w][kq * 68];
#pragma unroll
            for (int c = 0; c < 16; ++c) {
                float ha[4];
                *(float4*)ha = *(const float4*)(src + 4 * c);
#pragma unroll
                for (int i = 0; i < 4; ++i) {
                    float4 wv = wreg[c * 4 + i];
                    acc.x = fmaf(wv.x, ha[i], acc.x);
                    acc.y = fmaf(wv.y, ha[i], acc.y);
                    acc.z = fmaf(wv.z, ha[i], acc.z);
                    acc.w = fmaf(wv.w, ha[i], acc.w);
                }
            }
        }
        if (kq == 0) {
            acc.x += pre.x + breg.x; acc.y += pre.y + breg.y;
            acc.z += pre.z + breg.z; acc.w += pre.w + breg.w;
        }
        // butterfly over kq (lane bits 0-1): all 4 lanes end bitwise-identical
#pragma unroll
        for (int off = 1; off <= 2; off <<= 1) {
            acc.x += __shfl_xor(acc.x, off);
            acc.y += __shfl_xor(acc.y, off);
            acc.z += __shfl_xor(acc.z, off);
            acc.w += __shfl_xor(acc.w, off);
        }
        float ig = sigm(acc.x), fg = sigm(acc.y), gt = tanhf(acc.z), og = sigm(acc.w);
        creg = fg * creg + ig * gt;
        float hn = og * tanhf(creg);
        if (kq == 0)
            __hip_atomic_store(hdir + ((size_t)b * 512 + t) * 256 + j0 + j, hn,
                               __ATOMIC_RELAXED, __HIP_MEMORY_SCOPE_AGENT);
        // no barriers anywhere: hsh row is wave-private (lockstep), h slots
        // are write-once, the store IS the publication.
    }
}

// ---------------------------------------------------------------------------
// K3: emissions  em[b][t][k] = hcat . W_clf[k] + b_clf[k]
// ---------------------------------------------------------------------------
__global__ __launch_bounds__(256) void k_em(const float* __restrict__ hf,
                                            const float* __restrict__ hb,
                                            const float* __restrict__ Wclf,
                                            const float* __restrict__ bclf,
                                            const int* __restrict__ lengths,
                                            float* __restrict__ em) {
    extern __shared__ float4 wc4[];   // [128][32]: wc4[jq*32+ko] = Wclf[ko][4jq..+3]
    const int tid = threadIdx.x;
    for (int idx = tid; idx < 4096; idx += 256) {
        int jq = idx >> 5, ko = idx & 31;
        wc4[idx] = *(const float4*)(Wclf + (size_t)ko * 512 + jq * 4);
    }
    __syncthreads();
    const int r = tid >> 5, ko = tid & 31;
    const int m = blockIdx.x * 8 + r;
    const int b = m >> 9, t = m & 511;
    const int len = lengths[b];
    const int rev = (t < len) ? (len - 1 - t) : t;
    const float* hfr = hf + (size_t)m * 256;
    const float* hbr = hb + (size_t)(b * 512 + rev) * 256;
    float acc = bclf[ko];
#pragma unroll 4
    for (int jq = 0; jq < 64; ++jq) {
        float4 h4 = *(const float4*)(hfr + jq * 4);
        float4 ww = wc4[jq * 32 + ko];
        acc += h4.x * ww.x + h4.y * ww.y + h4.z * ww.z + h4.w * ww.w;
    }
#pragma unroll 4
    for (int jq = 0; jq < 64; ++jq) {
        float4 h4 = *(const float4*)(hbr + jq * 4);
        float4 ww = wc4[(64 + jq) * 32 + ko];
        acc += h4.x * ww.x + h4.y * ww.y + h4.z * ww.z + h4.w * ww.w;
    }
    em[(size_t)m * 32 + ko] = acc;
}

// ---------------------------------------------------------------------------
// K4: CRF forward (logZ, num) and Viterbi (+backtrace).
// ---------------------------------------------------------------------------
__global__ __launch_bounds__(64) void k_crfvit(const float* __restrict__ em,
                                               const int* __restrict__ targets,
                                               const int* __restrict__ lengths,
                                               const float* __restrict__ start_t,
                                               const float* __restrict__ end_t,
                                               const float* __restrict__ trans,
                                               float* __restrict__ numv,
                                               float* __restrict__ logZv,
                                               float* __restrict__ out) {
    __shared__ float trans_s[32][33];
    __shared__ float vec[32];
    __shared__ unsigned char hist[511 * 32];
    const int tid = threadIdx.x;
    const int b = blockIdx.x & 31;
    const int mode = blockIdx.x >> 5;
    for (int idx = tid; idx < 1024; idx += 64) trans_s[idx >> 5][idx & 31] = trans[idx];
    const int len = lengths[b];
    const float* emb = em + (size_t)b * 512 * 32;
    const int k = tid & 31, half = tid >> 5;
    if (tid < 32) vec[tid] = start_t[tid] + emb[tid];
    __syncthreads();

    if (mode == 0) {
        for (int t = 1; t < NT; ++t) {
            bool mv = t < len;
            int kp0 = half * 16;
            float m = -1e30f;
#pragma unroll 4
            for (int i = 0; i < 16; ++i)
                m = fmaxf(m, vec[kp0 + i] + trans_s[kp0 + i][k]);
            float m2 = fmaxf(m, __shfl_xor(m, 32));
            float ssum = 0.f;
#pragma unroll 4
            for (int i = 0; i < 16; ++i)
                ssum += __expf(vec[kp0 + i] + trans_s[kp0 + i][k] - m2);
            ssum += __shfl_xor(ssum, 32);
            float anew = m2 + __logf(ssum) + emb[t * 32 + k];
            __syncthreads();
            if (half == 0 && mv) vec[k] = anew;
            __syncthreads();
        }
        float val = (tid < 32) ? vec[tid] + end_t[tid] : -1e30f;
        float m = val;
#pragma unroll
        for (int off = 32; off >= 1; off >>= 1) m = fmaxf(m, __shfl_xor(m, off));
        float e = (tid < 32) ? __expf(val - m) : 0.f;
#pragma unroll
        for (int off = 32; off >= 1; off >>= 1) e += __shfl_xor(e, off);
        if (tid == 0) logZv[b] = m + __logf(e);
        // numerator
        const int* tg = targets + b * 512;
        float partial = 0.f;
        for (int t = 1 + tid; t < NT; t += 64) {
            if (t < len) {
                int y0 = tg[t - 1], y1 = tg[t];
                partial += trans_s[y0][y1] + emb[t * 32 + y1];
            }
        }
#pragma unroll
        for (int off = 32; off >= 1; off >>= 1) partial += __shfl_xor(partial, off);
        if (tid == 0) {
            int y00 = tg[0];
            int yl = tg[len - 1];
            numv[b] = partial + start_t[y00] + emb[y00] + end_t[yl];
        }
    } else {
        for (int t = 1; t < NT; ++t) {
            bool mv = t < len;
            int kp0 = half * 16;
            float e = emb[t * 32 + k];
            float m = -1e30f; int mi = kp0;
#pragma unroll 4
            for (int i = 0; i < 16; ++i) {
                float v = (vec[kp0 + i] + trans_s[kp0 + i][k]) + e;
                if (v > m) { m = v; mi = kp0 + i; }
            }
            float mo = __shfl_xor(m, 32);
            int io = __shfl_xor(mi, 32);
            float mlow = half ? mo : m;   int ilow = half ? io : mi;
            float mhigh = half ? m : mo;  int ihigh = half ? mi : io;
            float bm; int bi;
            if (mhigh > mlow) { bm = mhigh; bi = ihigh; } else { bm = mlow; bi = ilow; }
            __syncthreads();
            if (half == 0) {
                hist[(t - 1) * 32 + k] = (unsigned char)(mv ? bi : k);
                if (mv) vec[k] = bm;
            }
            __syncthreads();
        }
        float val = (tid < 32) ? vec[tid] + end_t[tid] : -1e30f;
        int idx = (tid < 32) ? tid : 63;
#pragma unroll
        for (int off = 32; off >= 1; off >>= 1) {
            float vo = __shfl_xor(val, off);
            int io = __shfl_xor(idx, off);
            if (vo > val || (vo == val && io < idx)) { val = vo; idx = io; }
        }
        int cur = idx;
        float* ob = out + 1 + (size_t)b * 512;
        if (tid == 0) ob[511] = (511 < len) ? (float)cur : 0.f;
        for (int t2 = 510; t2 >= 0; --t2) {
            cur = hist[t2 * 32 + cur];
            if (tid == 0) ob[t2] = (t2 < len) ? (float)cur : 0.f;
        }
    }
}

// ---------------------------------------------------------------------------
// K5: loss = -mean(num - logZ)
// ---------------------------------------------------------------------------
__global__ __launch_bounds__(64) void k_loss(const float* __restrict__ numv,
                                             const float* __restrict__ logZv,
                                             float* __restrict__ out) {
    int tid = threadIdx.x;
    float v = (tid < 32) ? (logZv[tid] - numv[tid]) : 0.f;
#pragma unroll
    for (int off = 32; off >= 1; off >>= 1) v += __shfl_xor(v, off);
    if (tid == 0) out[0] = v / 32.f;
}

// ---------------------------------------------------------------------------
extern "C" void kernel_launch(void* const* d_in, const int* in_sizes, int n_in,
                              void* d_out, int out_size, void* d_ws, size_t ws_size,
                              hipStream_t stream) {
    const float* x       = (const float*)d_in[0];
    const int*   lengths = (const int*)d_in[1];
    // d_in[2] = mask (recomputed from lengths)
    const int*   targets = (const int*)d_in[3];
    const float* W_ih_f  = (const float*)d_in[4];
    const float* W_hh_f  = (const float*)d_in[5];
    const float* b_f     = (const float*)d_in[6];
    const float* W_ih_b  = (const float*)d_in[7];
    const float* W_hh_b  = (const float*)d_in[8];
    const float* b_b     = (const float*)d_in[9];
    const float* W_clf   = (const float*)d_in[10];
    const float* b_clf   = (const float*)d_in[11];
    const float* start_t = (const float*)d_in[12];
    const float* end_t   = (const float*)d_in[13];
    const float* trans   = (const float*)d_in[14];
    float* out = (float*)d_out;
    float* ws = (float*)d_ws;

    float* C     = ws;                                   // 16384*2048
    float* h_f   = C + (size_t)16384 * 2048;             // 32*512*256
    float* h_b   = h_f + (size_t)32 * 512 * 256;         // 32*512*256
    float* em    = h_b + (size_t)32 * 512 * 256;         // 32*512*32
    float4* Wt4  = (float4*)(em + (size_t)32 * 512 * 32);// 131072 float4
    float* numv  = (float*)(Wt4 + 131072);               // 32
    float* logZv = numv + 32;                            // 32

    // Re-poison h buffers with the sentinel bit pattern every launch
    // (graph-replay safe: per-iteration reset of the data-flags).
    hipMemsetAsync(h_f, 0xFF, (size_t)2 * 32 * 512 * 256 * sizeof(float), stream);
    k_wt4<<<512, 256, 0, stream>>>(W_hh_f, W_hh_b, Wt4);
    k_sgemm<<<dim3(16, 128), 256, 0, stream>>>(x, W_ih_f, W_ih_b, C);
    k_lstm4<<<256, 256, 0, stream>>>(C, Wt4, b_f, b_b, lengths, h_f, h_b);
    k_em<<<2048, 256, 65536, stream>>>(h_f, h_b, W_clf, b_clf, lengths, em);
    k_crfvit<<<64, 64, 0, stream>>>(em, targets, lengths, start_t, end_t, trans, numv, logZv, out);
    k_loss<<<1, 64, 0, stream>>>(numv, logZv, out);
}